// Round 17
// baseline (527.349 us; speedup 1.0000x reference)
//
#include <hip/hip_runtime.h>

typedef _Float16 f16;
typedef _Float16 f16x8 __attribute__((ext_vector_type(8)));
typedef float f32x4 __attribute__((ext_vector_type(4)));

#define B_ 2
#define S_ 2048
#define D_ 512
#define H_ 8

__device__ inline void async_ld16(const void* g, void* l) {
  __builtin_amdgcn_global_load_lds((__attribute__((address_space(1))) void*)(g),
                                   (__attribute__((address_space(3))) void*)(l),
                                   16, 0, 0);
}

// monotone uint mapping of fp32 for atomicMax-based row max
__device__ inline unsigned fmap(float f) {
  unsigned u = __float_as_uint(f);
  return (u & 0x80000000u) ? ~u : (u | 0x80000000u);
}
__device__ inline float funmap(unsigned k) {
  return (k & 0x80000000u) ? __uint_as_float(k ^ 0x80000000u) : __uint_as_float(~k);
}

__global__ __launch_bounds__(256) void cvt_f16(const float* __restrict__ src,
                                               f16* __restrict__ dst, long n) {
  long i = (long)blockIdx.x * 256 + threadIdx.x;
  if (i >= n) return;
  dst[i] = (f16)src[i];
}

// [z][R][C] fp32 -> [z][C][R] fp16
__global__ __launch_bounds__(256) void transpose_f32(const float* __restrict__ src,
                                                     f16* __restrict__ dst, int R, int C) {
  __shared__ float t[32][33];
  size_t zoff = (size_t)blockIdx.z * R * C;
  const float* s = src + zoff;
  int tx = threadIdx.x;
  int ty = threadIdx.y;
  int c0 = blockIdx.x * 32, r0 = blockIdx.y * 32;
#pragma unroll
  for (int i = 0; i < 4; ++i)
    t[ty + i * 8][tx] = s[(size_t)(r0 + ty + i * 8) * C + c0 + tx];
  __syncthreads();
#pragma unroll
  for (int i = 0; i < 4; ++i)
    dst[zoff + (size_t)(c0 + ty + i * 8) * R + r0 + tx] = (f16)t[tx][ty + i * 8];
}

// out[i] = bo[i%D] + sum over nslab split-K partial slabs
__global__ __launch_bounds__(256) void reduce_out(const float* __restrict__ part,
                                                  const float* __restrict__ bo,
                                                  float* __restrict__ out, long n, int nslab) {
  long i = (long)blockIdx.x * 256 + threadIdx.x;
  if (i >= n) return;
  float v = bo[i & (D_ - 1)];
  for (int s = 0; s < nslab; ++s) v += part[(long)s * n + i];
  out[i] = v;
}

struct GemmArgs {
  const f16 *A, *Bm;
  void* C;
  const float* bias;
  unsigned* Mout;
  float* Mloc;
  int K, lda, ldb, ldc;
  int zbase, NG, PBG;
  long sAp, sAb, sAg, sAz;
  long sBp, sBb, sBg, sBz;
  long sCp, sCb, sCg, sCz;
  long sbp, sbb, sbg, sbz;
  long sMz, sMlz;
};

// NT GEMM fp16, fp32 acc. Swizzle s(r)=(r>>1)&3 (2-way = free; verified r10).
// PEXP: flash rescaling epilogue (local row max -> exp'd P via LDS repack).
template <typename OutT, int BIAS, bool PEXP>
__global__ __launch_bounds__(256) void gemm_nt(GemmArgs p) {
  int zloc = blockIdx.z;
  int zi = p.zbase + zloc;
  int pp = zi / p.PBG; int rz = zi - pp * p.PBG;
  int bb = rz / p.NG;  int g = rz - bb * p.NG;
  const f16* A  = p.A + (pp * p.sAp + bb * p.sAb + g * p.sAg + (long)zloc * p.sAz);
  const f16* Bm = p.Bm + (pp * p.sBp + bb * p.sBb + g * p.sBg + (long)zloc * p.sBz);
  OutT* C = (OutT*)p.C + (pp * p.sCp + bb * p.sCb + g * p.sCg + (long)zloc * p.sCz);
  const float* bias = nullptr;
  if (BIAS) bias = p.bias + (pp * p.sbp + bb * p.sbb + g * p.sbg + (long)zloc * p.sbz);
  unsigned* Mz = PEXP ? (p.Mout + (long)zloc * p.sMz) : nullptr;

  __shared__ f16 lA[4096];
  __shared__ f16 lB[4096];
  __shared__ float lMx[PEXP ? 256 : 1];
  __shared__ f16 lR[PEXP ? 32 * 136 : 1];

  int tid = threadIdx.x;
  int lane = tid & 63;
  int w = tid >> 6;
  int wm = (w >> 1) << 6;
  int wn = (w & 1) << 6;
  long bm = (long)blockIdx.y * 128;
  long bn = (long)blockIdx.x * 128;

  f32x4 acc[4][4] = {};
  int qd = lane >> 4;
  int fr = lane & 15;

  int q0 = tid, q1 = tid + 256;
  int r0s = q0 >> 2, c0s = (q0 & 3) ^ ((r0s >> 1) & 3);
  int r1s = q1 >> 2, c1s = (q1 & 3) ^ ((r1s >> 1) & 3);

  for (int k0 = 0; k0 < p.K; k0 += 32) {
    long oa0 = (bm + r0s) * (long)p.lda + (k0 + c0s * 8);
    long oa1 = (bm + r1s) * (long)p.lda + (k0 + c1s * 8);
    long ob0 = (bn + r0s) * (long)p.ldb + (k0 + c0s * 8);
    long ob1 = (bn + r1s) * (long)p.ldb + (k0 + c1s * 8);
    __syncthreads();
    async_ld16(A + oa0,  lA + (size_t)q0 * 8);
    async_ld16(A + oa1,  lA + (size_t)q1 * 8);
    async_ld16(Bm + ob0, lB + (size_t)q0 * 8);
    async_ld16(Bm + ob1, lB + (size_t)q1 * 8);
    __syncthreads();

    f16x8 ah[4], bh[4];
#pragma unroll
    for (int i = 0; i < 4; ++i) {
      int m = wm + i * 16 + fr;
      ah[i] = *(const f16x8*)(lA + ((size_t)m * 4 + (qd ^ ((m >> 1) & 3))) * 8);
      int n = wn + i * 16 + fr;
      bh[i] = *(const f16x8*)(lB + ((size_t)n * 4 + (qd ^ ((n >> 1) & 3))) * 8);
    }
#pragma unroll
    for (int i = 0; i < 4; ++i)
#pragma unroll
      for (int j = 0; j < 4; ++j)
        acc[i][j] = __builtin_amdgcn_mfma_f32_16x16x32_f16(ah[i], bh[j], acc[i][j], 0, 0, 0);
  }

  int rr0 = qd * 4;
  if (PEXP) {
#pragma unroll
    for (int i = 0; i < 4; ++i) {
#pragma unroll
      for (int r = 0; r < 4; ++r) {
        float v = fmaxf(fmaxf(acc[i][0][r], acc[i][1][r]),
                        fmaxf(acc[i][2][r], acc[i][3][r]));
        v = fmaxf(v, __shfl_xor(v, 1, 64));
        v = fmaxf(v, __shfl_xor(v, 2, 64));
        v = fmaxf(v, __shfl_xor(v, 4, 64));
        v = fmaxf(v, __shfl_xor(v, 8, 64));
        if (fr == 0) lMx[(w & 1) * 128 + wm + i * 16 + rr0 + r] = v;
      }
    }
    __syncthreads();
    if (tid < 128) {
      float ml = fmaxf(lMx[tid], lMx[128 + tid]);
      long row = bm + tid;
      p.Mloc[(long)zloc * p.sMlz + (long)blockIdx.x * S_ + row] = ml;
      atomicMax(Mz + row, fmap(ml));
    }
    int rowBase = (w >> 1) << 4;
#pragma unroll
    for (int i = 0; i < 4; ++i) {
      __syncthreads();
#pragma unroll
      for (int r = 0; r < 4; ++r) {
        int rl = wm + i * 16 + rr0 + r;
        float ml = fmaxf(lMx[rl], lMx[128 + rl]);
        int rowLoc = rowBase + rr0 + r;
#pragma unroll
        for (int j = 0; j < 4; ++j) {
          int col = wn + j * 16 + fr;
          lR[rowLoc * 136 + col] = (f16)__expf(acc[i][j][r] - ml);
        }
      }
      __syncthreads();
      int rowLoc = tid >> 3;
      int colLoc = (tid & 7) * 16;
      long grow = bm + ((rowLoc & 15) + i * 16) + ((long)(rowLoc >> 4) << 6);
      f16x8 v0 = *(const f16x8*)(lR + rowLoc * 136 + colLoc);
      f16x8 v1 = *(const f16x8*)(lR + rowLoc * 136 + colLoc + 8);
      f16* dst = (f16*)C + grow * (long)p.ldc + bn + colLoc;
      *(f16x8*)(dst) = v0;
      *(f16x8*)(dst + 8) = v1;
    }
  } else {
#pragma unroll
    for (int i = 0; i < 4; ++i) {
#pragma unroll
      for (int j = 0; j < 4; ++j) {
#pragma unroll
        for (int r = 0; r < 4; ++r) {
          long row = bm + wm + i * 16 + rr0 + r;
          long col = bn + wn + j * 16 + fr;
          float v = acc[i][j][r];
          if (BIAS == 1) v += bias[col];
          if (BIAS == 2) v += bias[row];
          C[row * (long)p.ldc + col] = (OutT)v;
        }
      }
    }
  }
}

// Fused Q+K+V projection dispatch (NB=2/GH=8 config only): z in [0,48),
// p = z>>4 in {Q,K,V^T}; flat 64-block tile decode per orientation.
// Overlaps V^T's tail with QK blocks; one launch boundary removed.
struct QkvArgs {
  const f16 *xh, *wqk, *wv;
  f16 *qk, *vT;
  const float *bqk, *bv;
};
__global__ __launch_bounds__(256) void qkv_proj(QkvArgs p) {
  const long SD = (long)S_ * D_, DD = (long)D_ * D_, DS = (long)D_ * S_;
  int zi = blockIdx.z;
  int pp = zi >> 4;
  int r = zi & 15;
  int b = r >> 3, h = r & 7;
  int bid = blockIdx.x;
  const f16 *A, *Bm;
  f16* C;
  const float* bias;
  long bm, bn;
  int ldc;
  bool biasRow;
  if (pp < 2) {
    A = p.xh + (long)b * SD;
    Bm = p.wqk + ((long)pp * 8 + h) * DD;
    C = p.qk + (long)zi * SD;  // zi == pp*16 + b*8 + h, matches [p][b][g] layout
    bias = p.bqk + ((long)pp * 8 + h) * D_;
    bm = (long)(bid >> 2) * 128; bn = (long)(bid & 3) * 128;
    ldc = D_; biasRow = false;
  } else {
    A = p.wv + (long)h * DD;
    Bm = p.xh + (long)b * SD;
    C = p.vT + (long)(b * 8 + h) * DS;
    bias = p.bv + (long)h * D_;
    bm = (long)(bid >> 4) * 128; bn = (long)(bid & 15) * 128;
    ldc = S_; biasRow = true;
  }

  __shared__ f16 lA[4096];
  __shared__ f16 lB[4096];

  int tid = threadIdx.x;
  int lane = tid & 63;
  int w = tid >> 6;
  int wm = (w >> 1) << 6;
  int wn = (w & 1) << 6;

  f32x4 acc[4][4] = {};
  int qd = lane >> 4;
  int fr = lane & 15;

  int q0 = tid, q1 = tid + 256;
  int r0s = q0 >> 2, c0s = (q0 & 3) ^ ((r0s >> 1) & 3);
  int r1s = q1 >> 2, c1s = (q1 & 3) ^ ((r1s >> 1) & 3);

  for (int k0 = 0; k0 < D_; k0 += 32) {
    long oa0 = (bm + r0s) * (long)D_ + (k0 + c0s * 8);
    long oa1 = (bm + r1s) * (long)D_ + (k0 + c1s * 8);
    long ob0 = (bn + r0s) * (long)D_ + (k0 + c0s * 8);
    long ob1 = (bn + r1s) * (long)D_ + (k0 + c1s * 8);
    __syncthreads();
    async_ld16(A + oa0,  lA + (size_t)q0 * 8);
    async_ld16(A + oa1,  lA + (size_t)q1 * 8);
    async_ld16(Bm + ob0, lB + (size_t)q0 * 8);
    async_ld16(Bm + ob1, lB + (size_t)q1 * 8);
    __syncthreads();

    f16x8 ah[4], bh[4];
#pragma unroll
    for (int i = 0; i < 4; ++i) {
      int m = wm + i * 16 + fr;
      ah[i] = *(const f16x8*)(lA + ((size_t)m * 4 + (qd ^ ((m >> 1) & 3))) * 8);
      int n = wn + i * 16 + fr;
      bh[i] = *(const f16x8*)(lB + ((size_t)n * 4 + (qd ^ ((n >> 1) & 3))) * 8);
    }
#pragma unroll
    for (int i = 0; i < 4; ++i)
#pragma unroll
      for (int j = 0; j < 4; ++j)
        acc[i][j] = __builtin_amdgcn_mfma_f32_16x16x32_f16(ah[i], bh[j], acc[i][j], 0, 0, 0);
  }

  int rr0 = qd * 4;
#pragma unroll
  for (int i = 0; i < 4; ++i) {
#pragma unroll
    for (int j = 0; j < 4; ++j) {
#pragma unroll
      for (int r = 0; r < 4; ++r) {
        long row = bm + wm + i * 16 + rr0 + r;
        long col = bn + wn + j * 16 + fr;
        float v = acc[i][j][r] + (biasRow ? bias[row] : bias[col]);
        C[row * (long)ldc + col] = (f16)v;
      }
    }
  }
}

// Flash-PV with pre-exp'd P, 64 s-rows x 128 e-cols (4 waves x 32 cols):
// grid (4,32,GS) ~= 1024 blocks -> 4 blocks/CU (r16 at 256-col was exactly
// 2/CU, grid-limited). V traffic unchanged (blocks partition e). 12 KB LDS.
struct PvArgs {
  const f16* S; const unsigned* M; const float* Ml; const f16* V; f16* C;
  int ldc, zbase, NG;
  long sVz, sCb, sCg;
};
__global__ __launch_bounds__(256) void pv_flash(PvArgs p) {
  int zloc = blockIdx.z;
  int zi = p.zbase + zloc;
  int bb = zi / p.NG; int g = zi - bb * p.NG;
  const f16* Sm = p.S + (long)zloc * S_ * S_;
  const unsigned* Mz = p.M + (long)zloc * S_;
  const float* Ml = p.Ml + (long)zloc * 16 * S_;
  const f16* V = p.V + (long)zloc * p.sVz;
  f16* C = p.C + bb * p.sCb + g * p.sCg;

  __shared__ f16 lP[64 * 32];    // staged P (A-fragment layout) 4 KB
  __shared__ f16 lV[128 * 32];   // V tile (B-fragment layout) 8 KB

  int tid = threadIdx.x;
  int lane = tid & 63;
  int w = tid >> 6;
  long bm = (long)blockIdx.y * 64;   // s-row origin
  long bn = (long)blockIdx.x * 128;  // e origin of the block
  int e0 = w << 5;                   // wave's 32-col e origin within block

  int qd = lane >> 4;
  int fr = lane & 15;

  f32x4 acc[4][2] = {};
  f32x4 lacc[4] = {};
  f16x8 ones;
#pragma unroll
  for (int j = 0; j < 8; ++j) ones[j] = (f16)1.0f;

  float mg[4];
#pragma unroll
  for (int i = 0; i < 4; ++i) mg[i] = funmap(Mz[bm + i * 16 + fr]);
  f16 al16[4];

  int rs = tid >> 2, cs = (tid & 3) ^ ((rs >> 1) & 3);  // P staging map
  int rv1 = (tid + 256) >> 2, cv1 = ((tid + 256) & 3) ^ ((rv1 >> 1) & 3);

  for (int k0 = 0; k0 < S_; k0 += 32) {
    if ((k0 & 127) == 0) {  // new 128-col scores block: refresh alpha
      int cb = k0 >> 7;
#pragma unroll
      for (int i = 0; i < 4; ++i)
        al16[i] = (f16)__expf(Ml[cb * S_ + bm + i * 16 + fr] - mg[i]);
    }
    __syncthreads();
    async_ld16(Sm + (bm + rs) * (long)S_ + (k0 + cs * 8), lP + (size_t)tid * 8);
    async_ld16(V + (bn + rs) * (long)S_ + (k0 + cs * 8), lV + (size_t)tid * 8);
    async_ld16(V + (bn + rv1) * (long)S_ + (k0 + cv1 * 8), lV + (size_t)(tid + 256) * 8);
    __syncthreads();

    f16x8 ah[4], bh[2];
#pragma unroll
    for (int i = 0; i < 4; ++i) {
      int m = i * 16 + fr;
      ah[i] = *(const f16x8*)(lP + ((size_t)m * 4 + (qd ^ ((m >> 1) & 3))) * 8);
#pragma unroll
      for (int j = 0; j < 8; ++j) ah[i][j] *= al16[i];
    }
#pragma unroll
    for (int j = 0; j < 2; ++j) {
      int n = e0 + j * 16 + fr;
      bh[j] = *(const f16x8*)(lV + ((size_t)n * 4 + (qd ^ ((n >> 1) & 3))) * 8);
    }
#pragma unroll
    for (int i = 0; i < 4; ++i) {
      lacc[i] = __builtin_amdgcn_mfma_f32_16x16x32_f16(ah[i], ones, lacc[i], 0, 0, 0);
#pragma unroll
      for (int j = 0; j < 2; ++j)
        acc[i][j] = __builtin_amdgcn_mfma_f32_16x16x32_f16(ah[i], bh[j], acc[i][j], 0, 0, 0);
    }
  }

  int rr0 = (lane >> 4) * 4;
#pragma unroll
  for (int i = 0; i < 4; ++i) {
    float inv[4];
#pragma unroll
    for (int r = 0; r < 4; ++r) inv[r] = 1.0f / lacc[i][r];
#pragma unroll
    for (int j = 0; j < 2; ++j) {
#pragma unroll
      for (int r = 0; r < 4; ++r) {
        long row = bm + i * 16 + rr0 + r;
        long col = bn + e0 + j * 16 + fr;
        C[row * (long)p.ldc + col] = (f16)(acc[i][j][r] * inv[r]);
      }
    }
  }
}

extern "C" void kernel_launch(void* const* d_in, const int* in_sizes, int n_in,
                              void* d_out, int out_size, void* d_ws, size_t ws_size,
                              hipStream_t stream) {
  const float* x  = (const float*)d_in[0];
  const float* Wq = (const float*)d_in[1];
  const float* bq = (const float*)d_in[2];
  const float* Wk = (const float*)d_in[3];
  const float* bk = (const float*)d_in[4];
  const float* Wv = (const float*)d_in[5];
  const float* bv = (const float*)d_in[6];
  const float* Wo = (const float*)d_in[7];
  const float* bo = (const float*)d_in[8];
  float* out = (float*)d_out;

  auto al = [](size_t v) { return (v + 255) & ~(size_t)255; };
  const size_t eX = (size_t)B_ * S_ * D_;
  const size_t eW = (size_t)H_ * D_ * D_;
  const size_t eSS = (size_t)S_ * S_;
  const long SD = (long)S_ * D_;
  const long DD = (long)D_ * D_;
  const long DS = (long)D_ * S_;

  size_t fixed = al(eX * 2) + al(2 * eW * 2) + al(eW * 2) + al(eW * 2)
               + al(2ULL * H_ * D_ * 4);
  int NB = 1, GH = 1, GS = 1; bool found = false;
  for (int nb = 2; nb >= 1 && !found; --nb)
    for (int gh = 8; gh >= 1 && !found; gh >>= 1)
      for (int gs = nb * gh; gs >= 1 && !found; gs >>= 1) {
        size_t need = fixed + al((size_t)nb * S_ * H_ * D_ * 2)
                    + al(2ULL * nb * gh * S_ * D_ * 2)
                    + al((size_t)nb * gh * D_ * S_ * 2)
                    + al(4ULL * nb * SD * 4)
                    + al((size_t)gs * eSS * 2) + al((size_t)gs * S_ * 4)
                    + al((size_t)gs * 16 * S_ * 4);
        if (need <= ws_size) { NB = nb; GH = gh; GS = gs; found = true; }
      }

  char* p0 = (char*)d_ws;
  size_t off = 0;
  f16* xh    = (f16*)(p0 + off); off += al(eX * 2);
  f16* wqk   = (f16*)(p0 + off); off += al(2 * eW * 2);
  f16* wv    = (f16*)(p0 + off); off += al(eW * 2);
  f16* wo    = (f16*)(p0 + off); off += al(eW * 2);
  float* bqk = (float*)(p0 + off); off += al(2ULL * H_ * D_ * 4);
  f16* catb  = (f16*)(p0 + off); off += al((size_t)NB * S_ * H_ * D_ * 2);
  f16* qk    = (f16*)(p0 + off); off += al(2ULL * NB * GH * S_ * D_ * 2);
  f16* vT    = (f16*)(p0 + off); off += al((size_t)NB * GH * D_ * S_ * 2);
  float* opart = (float*)(p0 + off); off += al(4ULL * NB * SD * 4);
  f16* scores = (f16*)(p0 + off); off += al((size_t)GS * eSS * 2);
  unsigned* rowmax = (unsigned*)(p0 + off); off += al((size_t)GS * S_ * 4);
  float* mloc = (float*)(p0 + off);

  // ---- prep ----
  cvt_f16<<<dim3((unsigned)((eX + 255) / 256)), 256, 0, stream>>>(x, xh, (long)eX);
  dim3 tb(32, 8, 1);
  transpose_f32<<<dim3(16, 16, H_), tb, 0, stream>>>(Wq, wqk, D_, D_);
  transpose_f32<<<dim3(16, 16, H_), tb, 0, stream>>>(Wk, wqk + eW, D_, D_);
  transpose_f32<<<dim3(16, 16, H_), tb, 0, stream>>>(Wv, wv, D_, D_);
  transpose_f32<<<dim3(16, 128, 1), tb, 0, stream>>>(Wo, wo, H_ * D_, D_);
  hipMemcpyAsync(bqk, bq, (size_t)H_ * D_ * 4, hipMemcpyDeviceToDevice, stream);
  hipMemcpyAsync(bqk + H_ * D_, bk, (size_t)H_ * D_ * 4, hipMemcpyDeviceToDevice, stream);

  for (int b0 = 0; b0 < B_; b0 += NB) {
    for (int h0 = 0; h0 < H_; h0 += GH) {
      if (NB == 2 && GH == 8) {  // fused Q+K+V^T projection (verified config)
        QkvArgs a{xh, wqk, wv, qk, vT, bqk, bv};
        qkv_proj<<<dim3(64, 1, 48), 256, 0, stream>>>(a);
      } else {
        {  // Q+K projections
          GemmArgs a{};
          a.A = xh + (long)b0 * SD;
          a.Bm = wqk + (long)h0 * DD;
          a.C = qk; a.bias = bqk + (long)h0 * D_;
          a.K = D_; a.lda = D_; a.ldb = D_; a.ldc = D_;
          a.zbase = 0; a.NG = GH; a.PBG = NB * GH;
          a.sAb = SD;
          a.sBp = (long)H_ * DD; a.sBg = DD;
          a.sCz = SD;
          a.sbp = (long)H_ * D_; a.sbg = D_;
          gemm_nt<f16, 1, false><<<dim3(4, 16, 2 * NB * GH), 256, 0, stream>>>(a);
        }
        {  // V^T
          GemmArgs a{};
          a.A = wv + (long)h0 * DD; a.Bm = xh + (long)b0 * SD;
          a.C = vT; a.bias = bv + (long)h0 * D_;
          a.K = D_; a.lda = D_; a.ldb = D_; a.ldc = S_;
          a.zbase = 0; a.NG = GH; a.PBG = NB * GH;
          a.sAg = DD;
          a.sBb = SD;
          a.sCz = DS;
          a.sbg = D_;
          gemm_nt<f16, 2, false><<<dim3(16, 4, NB * GH), 256, 0, stream>>>(a);
        }
      }
      for (int g0 = 0; g0 < NB * GH; g0 += GS) {
        hipMemsetAsync(rowmax, 0, (size_t)GS * S_ * 4, stream);
        {  // scores -> P_loc = exp(s - m_loc) f16, Mloc, rowmax
          GemmArgs a{};
          a.A = qk + (long)g0 * SD;
          a.Bm = qk + ((long)NB * GH + g0) * SD;
          a.C = scores; a.Mout = rowmax; a.Mloc = mloc;
          a.K = D_; a.lda = D_; a.ldb = D_; a.ldc = S_;
          a.zbase = g0; a.NG = GH; a.PBG = NB * GH;
          a.sAz = SD; a.sBz = SD; a.sCz = (long)eSS; a.sMz = S_;
          a.sMlz = 16L * S_;
          gemm_nt<f16, 0, true><<<dim3(16, 16, GS), 256, 0, stream>>>(a);
        }
        {  // flash PV (rescale-only, 128-col e-blocks): catb = P·V / l
          PvArgs a{};
          a.S = scores; a.M = rowmax; a.Ml = mloc; a.V = vT + (long)g0 * DS;
          a.C = catb + (long)h0 * D_;
          a.ldc = H_ * D_; a.zbase = g0; a.NG = GH;
          a.sVz = DS; a.sCb = (long)S_ * H_ * D_; a.sCg = D_;
          pv_flash<<<dim3(4, S_ / 64, GS), 256, 0, stream>>>(a);
        }
      }
    }
    {  // out-proj split-K (4 slabs of 1024)
      GemmArgs a{};
      a.A = catb; a.Bm = wo;
      a.C = opart;
      a.K = 1024; a.lda = H_ * D_; a.ldb = H_ * D_; a.ldc = D_;
      a.zbase = 0; a.NG = 4; a.PBG = NB * 4;
      a.sAb = (long)S_ * H_ * D_; a.sAg = 1024;
      a.sBg = 1024;
      a.sCb = SD; a.sCg = (long)NB * SD;
      gemm_nt<float, 0, false><<<dim3(4, 16, NB * 4), 256, 0, stream>>>(a);
    }
    reduce_out<<<dim3((unsigned)(((long)NB * SD + 255) / 256)), 256, 0, stream>>>(
        opart, bo, out + (long)b0 * SD, (long)NB * SD, 4);
  }
}

// Round 18
// 498.158 us; speedup vs baseline: 1.0586x; 1.0586x over previous
//
#include <hip/hip_runtime.h>

typedef _Float16 f16;
typedef _Float16 f16x8 __attribute__((ext_vector_type(8)));
typedef float f32x4 __attribute__((ext_vector_type(4)));

#define B_ 2
#define S_ 2048
#define D_ 512
#define H_ 8

__device__ inline void async_ld16(const void* g, void* l) {
  __builtin_amdgcn_global_load_lds((__attribute__((address_space(1))) void*)(g),
                                   (__attribute__((address_space(3))) void*)(l),
                                   16, 0, 0);
}

__global__ __launch_bounds__(256) void cvt_f16(const float* __restrict__ src,
                                               f16* __restrict__ dst, long n) {
  long i = (long)blockIdx.x * 256 + threadIdx.x;
  if (i >= n) return;
  dst[i] = (f16)src[i];
}

// [z][R][C] fp32 -> [z][C][R] fp16
__global__ __launch_bounds__(256) void transpose_f32(const float* __restrict__ src,
                                                     f16* __restrict__ dst, int R, int C) {
  __shared__ float t[32][33];
  size_t zoff = (size_t)blockIdx.z * R * C;
  const float* s = src + zoff;
  int tx = threadIdx.x;
  int ty = threadIdx.y;
  int c0 = blockIdx.x * 32, r0 = blockIdx.y * 32;
#pragma unroll
  for (int i = 0; i < 4; ++i)
    t[ty + i * 8][tx] = s[(size_t)(r0 + ty + i * 8) * C + c0 + tx];
  __syncthreads();
#pragma unroll
  for (int i = 0; i < 4; ++i)
    dst[zoff + (size_t)(c0 + ty + i * 8) * R + r0 + tx] = (f16)t[tx][ty + i * 8];
}

// out[i] = bo[i%D] + sum over nslab split-K partial slabs
__global__ __launch_bounds__(256) void reduce_out(const float* __restrict__ part,
                                                  const float* __restrict__ bo,
                                                  float* __restrict__ out, long n, int nslab) {
  long i = (long)blockIdx.x * 256 + threadIdx.x;
  if (i >= n) return;
  float v = bo[i & (D_ - 1)];
  for (int s = 0; s < nslab; ++s) v += part[(long)s * n + i];
  out[i] = v;
}

struct GemmArgs {
  const f16 *A, *Bm;
  void* C;
  const float* bias;
  float* Mloc;   // PEXP: per-(colblock,row) local max, non-atomic
  int K, lda, ldb, ldc;
  int zbase, NG, PBG;
  long sAp, sAb, sAg, sAz;
  long sBp, sBb, sBg, sBz;
  long sCp, sCb, sCg, sCz;
  long sbp, sbb, sbg, sbz;
  long sMlz;
};

// NT GEMM fp16, fp32 acc. Swizzle s(r)=(r>>1)&3 (2-way = free; verified r10).
// PEXP: flash rescaling epilogue — local row max m_loc over the block's 128
// cols, store P = exp(s - m_loc) f16 via LDS repack (coalesced f16x8 stores),
// write Mloc[cb][row]. No global atomics (pv derives the global max from Mloc).
template <typename OutT, int BIAS, bool PEXP>
__global__ __launch_bounds__(256) void gemm_nt(GemmArgs p) {
  int zloc = blockIdx.z;
  int zi = p.zbase + zloc;
  int pp = zi / p.PBG; int rz = zi - pp * p.PBG;
  int bb = rz / p.NG;  int g = rz - bb * p.NG;
  const f16* A  = p.A + (pp * p.sAp + bb * p.sAb + g * p.sAg + (long)zloc * p.sAz);
  const f16* Bm = p.Bm + (pp * p.sBp + bb * p.sBb + g * p.sBg + (long)zloc * p.sBz);
  OutT* C = (OutT*)p.C + (pp * p.sCp + bb * p.sCb + g * p.sCg + (long)zloc * p.sCz);
  const float* bias = nullptr;
  if (BIAS) bias = p.bias + (pp * p.sbp + bb * p.sbb + g * p.sbg + (long)zloc * p.sbz);

  __shared__ f16 lA[4096];
  __shared__ f16 lB[4096];
  __shared__ float lMx[PEXP ? 256 : 1];
  __shared__ f16 lR[PEXP ? 32 * 136 : 1];

  int tid = threadIdx.x;
  int lane = tid & 63;
  int w = tid >> 6;
  int wm = (w >> 1) << 6;
  int wn = (w & 1) << 6;
  long bm = (long)blockIdx.y * 128;
  long bn = (long)blockIdx.x * 128;

  f32x4 acc[4][4] = {};
  int qd = lane >> 4;
  int fr = lane & 15;

  int q0 = tid, q1 = tid + 256;
  int r0s = q0 >> 2, c0s = (q0 & 3) ^ ((r0s >> 1) & 3);
  int r1s = q1 >> 2, c1s = (q1 & 3) ^ ((r1s >> 1) & 3);

  for (int k0 = 0; k0 < p.K; k0 += 32) {
    long oa0 = (bm + r0s) * (long)p.lda + (k0 + c0s * 8);
    long oa1 = (bm + r1s) * (long)p.lda + (k0 + c1s * 8);
    long ob0 = (bn + r0s) * (long)p.ldb + (k0 + c0s * 8);
    long ob1 = (bn + r1s) * (long)p.ldb + (k0 + c1s * 8);
    __syncthreads();
    async_ld16(A + oa0,  lA + (size_t)q0 * 8);
    async_ld16(A + oa1,  lA + (size_t)q1 * 8);
    async_ld16(Bm + ob0, lB + (size_t)q0 * 8);
    async_ld16(Bm + ob1, lB + (size_t)q1 * 8);
    __syncthreads();

    f16x8 ah[4], bh[4];
#pragma unroll
    for (int i = 0; i < 4; ++i) {
      int m = wm + i * 16 + fr;
      ah[i] = *(const f16x8*)(lA + ((size_t)m * 4 + (qd ^ ((m >> 1) & 3))) * 8);
      int n = wn + i * 16 + fr;
      bh[i] = *(const f16x8*)(lB + ((size_t)n * 4 + (qd ^ ((n >> 1) & 3))) * 8);
    }
#pragma unroll
    for (int i = 0; i < 4; ++i)
#pragma unroll
      for (int j = 0; j < 4; ++j)
        acc[i][j] = __builtin_amdgcn_mfma_f32_16x16x32_f16(ah[i], bh[j], acc[i][j], 0, 0, 0);
  }

  int rr0 = qd * 4;
  if (PEXP) {
#pragma unroll
    for (int i = 0; i < 4; ++i) {
#pragma unroll
      for (int r = 0; r < 4; ++r) {
        float v = fmaxf(fmaxf(acc[i][0][r], acc[i][1][r]),
                        fmaxf(acc[i][2][r], acc[i][3][r]));
        v = fmaxf(v, __shfl_xor(v, 1, 64));
        v = fmaxf(v, __shfl_xor(v, 2, 64));
        v = fmaxf(v, __shfl_xor(v, 4, 64));
        v = fmaxf(v, __shfl_xor(v, 8, 64));
        if (fr == 0) lMx[(w & 1) * 128 + wm + i * 16 + rr0 + r] = v;
      }
    }
    __syncthreads();
    if (tid < 128) {
      float ml = fmaxf(lMx[tid], lMx[128 + tid]);
      p.Mloc[(long)zloc * p.sMlz + (long)blockIdx.x * S_ + bm + tid] = ml;
    }
    int rowBase = (w >> 1) << 4;
#pragma unroll
    for (int i = 0; i < 4; ++i) {
      __syncthreads();
#pragma unroll
      for (int r = 0; r < 4; ++r) {
        int rl = wm + i * 16 + rr0 + r;
        float ml = fmaxf(lMx[rl], lMx[128 + rl]);
        int rowLoc = rowBase + rr0 + r;
#pragma unroll
        for (int j = 0; j < 4; ++j) {
          int col = wn + j * 16 + fr;
          lR[rowLoc * 136 + col] = (f16)__expf(acc[i][j][r] - ml);
        }
      }
      __syncthreads();
      int rowLoc = tid >> 3;
      int colLoc = (tid & 7) * 16;
      long grow = bm + ((rowLoc & 15) + i * 16) + ((long)(rowLoc >> 4) << 6);
      f16x8 v0 = *(const f16x8*)(lR + rowLoc * 136 + colLoc);
      f16x8 v1 = *(const f16x8*)(lR + rowLoc * 136 + colLoc + 8);
      f16* dst = (f16*)C + grow * (long)p.ldc + bn + colLoc;
      *(f16x8*)(dst) = v0;
      *(f16x8*)(dst + 8) = v1;
    }
  } else {
#pragma unroll
    for (int i = 0; i < 4; ++i) {
#pragma unroll
      for (int j = 0; j < 4; ++j) {
#pragma unroll
        for (int r = 0; r < 4; ++r) {
          long row = bm + wm + i * 16 + rr0 + r;
          long col = bn + wn + j * 16 + fr;
          float v = acc[i][j][r];
          if (BIAS == 1) v += bias[col];
          if (BIAS == 2) v += bias[row];
          C[row * (long)p.ldc + col] = (OutT)v;
        }
      }
    }
  }
}

// Fused Q+K+V projection dispatch (NB=2/GH=8 config): z in [0,48),
// p = z>>4 in {Q,K,V^T}; flat 64/256-block tile decode per orientation.
struct QkvArgs {
  const f16 *xh, *wqk, *wv;
  f16 *qk, *vT;
  const float *bqk, *bv;
};
__global__ __launch_bounds__(256) void qkv_proj(QkvArgs p) {
  const long SD = (long)S_ * D_, DD = (long)D_ * D_, DS = (long)D_ * S_;
  int zi = blockIdx.z;
  int pp = zi >> 4;
  int r = zi & 15;
  int b = r >> 3, h = r & 7;
  int bid = blockIdx.x;
  const f16 *A, *Bm;
  f16* C;
  const float* bias;
  long bm, bn;
  int ldc;
  bool biasRow;
  if (pp < 2) {
    A = p.xh + (long)b * SD;
    Bm = p.wqk + ((long)pp * 8 + h) * DD;
    C = p.qk + (long)zi * SD;
    bias = p.bqk + ((long)pp * 8 + h) * D_;
    bm = (long)(bid >> 2) * 128; bn = (long)(bid & 3) * 128;
    ldc = D_; biasRow = false;
  } else {
    A = p.wv + (long)h * DD;
    Bm = p.xh + (long)b * SD;
    C = p.vT + (long)(b * 8 + h) * DS;
    bias = p.bv + (long)h * D_;
    bm = (long)(bid >> 4) * 128; bn = (long)(bid & 15) * 128;
    ldc = S_; biasRow = true;
  }

  __shared__ f16 lA[4096];
  __shared__ f16 lB[4096];

  int tid = threadIdx.x;
  int lane = tid & 63;
  int w = tid >> 6;
  int wm = (w >> 1) << 6;
  int wn = (w & 1) << 6;

  f32x4 acc[4][4] = {};
  int qd = lane >> 4;
  int fr = lane & 15;

  int q0 = tid, q1 = tid + 256;
  int r0s = q0 >> 2, c0s = (q0 & 3) ^ ((r0s >> 1) & 3);
  int r1s = q1 >> 2, c1s = (q1 & 3) ^ ((r1s >> 1) & 3);

  for (int k0 = 0; k0 < D_; k0 += 32) {
    long oa0 = (bm + r0s) * (long)D_ + (k0 + c0s * 8);
    long oa1 = (bm + r1s) * (long)D_ + (k0 + c1s * 8);
    long ob0 = (bn + r0s) * (long)D_ + (k0 + c0s * 8);
    long ob1 = (bn + r1s) * (long)D_ + (k0 + c1s * 8);
    __syncthreads();
    async_ld16(A + oa0,  lA + (size_t)q0 * 8);
    async_ld16(A + oa1,  lA + (size_t)q1 * 8);
    async_ld16(Bm + ob0, lB + (size_t)q0 * 8);
    async_ld16(Bm + ob1, lB + (size_t)q1 * 8);
    __syncthreads();

    f16x8 ah[4], bh[4];
#pragma unroll
    for (int i = 0; i < 4; ++i) {
      int m = wm + i * 16 + fr;
      ah[i] = *(const f16x8*)(lA + ((size_t)m * 4 + (qd ^ ((m >> 1) & 3))) * 8);
      int n = wn + i * 16 + fr;
      bh[i] = *(const f16x8*)(lB + ((size_t)n * 4 + (qd ^ ((n >> 1) & 3))) * 8);
    }
#pragma unroll
    for (int i = 0; i < 4; ++i)
#pragma unroll
      for (int j = 0; j < 4; ++j)
        acc[i][j] = __builtin_amdgcn_mfma_f32_16x16x32_f16(ah[i], bh[j], acc[i][j], 0, 0, 0);
  }

  int rr0 = qd * 4;
#pragma unroll
  for (int i = 0; i < 4; ++i) {
#pragma unroll
    for (int j = 0; j < 4; ++j) {
#pragma unroll
      for (int r = 0; r < 4; ++r) {
        long row = bm + wm + i * 16 + rr0 + r;
        long col = bn + wn + j * 16 + fr;
        float v = acc[i][j][r] + (biasRow ? bias[row] : bias[col]);
        C[row * (long)ldc + col] = (f16)v;
      }
    }
  }
}

// Flash-PV with pre-exp'd P (r16 256-col core): O = sum_t P*alpha * V / l.
// Global row max derived from Mloc (max over 16 col-blocks) — no atomics.
struct PvArgs {
  const f16* S; const float* Ml; const f16* V; f16* C;
  int ldc, zbase, NG;
  long sVz, sCb, sCg;
};
__global__ __launch_bounds__(256) void pv_flash(PvArgs p) {
  int zloc = blockIdx.z;
  int zi = p.zbase + zloc;
  int bb = zi / p.NG; int g = zi - bb * p.NG;
  const f16* Sm = p.S + (long)zloc * S_ * S_;
  const float* Ml = p.Ml + (long)zloc * 16 * S_;
  const f16* V = p.V + (long)zloc * p.sVz;
  f16* C = p.C + bb * p.sCb + g * p.sCg;

  __shared__ f16 lP[64 * 32];    // staged P (A-fragment layout) 4 KB
  __shared__ f16 lV[256 * 32];   // V tile (B-fragment layout) 16 KB

  int tid = threadIdx.x;
  int lane = tid & 63;
  int w = tid >> 6;
  long bm = (long)blockIdx.y * 64;
  long bn = (long)blockIdx.x * 256;
  int e0 = w << 6;

  int qd = lane >> 4;
  int fr = lane & 15;

  f32x4 acc[4][4] = {};
  f32x4 lacc[4] = {};
  f16x8 ones;
#pragma unroll
  for (int j = 0; j < 8; ++j) ones[j] = (f16)1.0f;

  float mg[4];
#pragma unroll
  for (int i = 0; i < 4; ++i) {
    float m = -1e30f;
#pragma unroll
    for (int cb = 0; cb < 16; ++cb)
      m = fmaxf(m, Ml[cb * S_ + bm + i * 16 + fr]);
    mg[i] = m;
  }
  f16 al16[4];

  int rs = tid >> 2, cs = (tid & 3) ^ ((rs >> 1) & 3);

  for (int k0 = 0; k0 < S_; k0 += 32) {
    if ((k0 & 127) == 0) {
      int cb = k0 >> 7;
#pragma unroll
      for (int i = 0; i < 4; ++i)
        al16[i] = (f16)__expf(Ml[cb * S_ + bm + i * 16 + fr] - mg[i]);
    }
    __syncthreads();
    async_ld16(Sm + (bm + rs) * (long)S_ + (k0 + cs * 8), lP + (size_t)tid * 8);
#pragma unroll
    for (int j = 0; j < 4; ++j) {
      int q = j * 256 + tid;
      int rv = q >> 2, cv = (q & 3) ^ ((rv >> 1) & 3);
      async_ld16(V + (bn + rv) * (long)S_ + (k0 + cv * 8), lV + (size_t)q * 8);
    }
    __syncthreads();

    f16x8 ah[4], bh[4];
#pragma unroll
    for (int i = 0; i < 4; ++i) {
      int m = i * 16 + fr;
      ah[i] = *(const f16x8*)(lP + ((size_t)m * 4 + (qd ^ ((m >> 1) & 3))) * 8);
#pragma unroll
      for (int j = 0; j < 8; ++j) ah[i][j] *= al16[i];
    }
#pragma unroll
    for (int j = 0; j < 4; ++j) {
      int n = e0 + j * 16 + fr;
      bh[j] = *(const f16x8*)(lV + ((size_t)n * 4 + (qd ^ ((n >> 1) & 3))) * 8);
    }
#pragma unroll
    for (int i = 0; i < 4; ++i) {
      lacc[i] = __builtin_amdgcn_mfma_f32_16x16x32_f16(ah[i], ones, lacc[i], 0, 0, 0);
#pragma unroll
      for (int j = 0; j < 4; ++j)
        acc[i][j] = __builtin_amdgcn_mfma_f32_16x16x32_f16(ah[i], bh[j], acc[i][j], 0, 0, 0);
    }
  }

  int rr0 = (lane >> 4) * 4;
#pragma unroll
  for (int i = 0; i < 4; ++i) {
    float inv[4];
#pragma unroll
    for (int r = 0; r < 4; ++r) inv[r] = 1.0f / lacc[i][r];
#pragma unroll
    for (int j = 0; j < 4; ++j) {
#pragma unroll
      for (int r = 0; r < 4; ++r) {
        long row = bm + i * 16 + rr0 + r;
        long col = bn + e0 + j * 16 + fr;
        C[row * (long)p.ldc + col] = (f16)(acc[i][j][r] * inv[r]);
      }
    }
  }
}

extern "C" void kernel_launch(void* const* d_in, const int* in_sizes, int n_in,
                              void* d_out, int out_size, void* d_ws, size_t ws_size,
                              hipStream_t stream) {
  const float* x  = (const float*)d_in[0];
  const float* Wq = (const float*)d_in[1];
  const float* bq = (const float*)d_in[2];
  const float* Wk = (const float*)d_in[3];
  const float* bk = (const float*)d_in[4];
  const float* Wv = (const float*)d_in[5];
  const float* bv = (const float*)d_in[6];
  const float* Wo = (const float*)d_in[7];
  const float* bo = (const float*)d_in[8];
  float* out = (float*)d_out;

  auto al = [](size_t v) { return (v + 255) & ~(size_t)255; };
  const size_t eX = (size_t)B_ * S_ * D_;
  const size_t eW = (size_t)H_ * D_ * D_;
  const size_t eSS = (size_t)S_ * S_;
  const long SD = (long)S_ * D_;
  const long DD = (long)D_ * D_;
  const long DS = (long)D_ * S_;

  size_t fixed = al(eX * 2) + al(2 * eW * 2) + al(eW * 2) + al(eW * 2)
               + al(2ULL * H_ * D_ * 4);
  int NB = 1, GH = 1, GS = 1; bool found = false;
  for (int nb = 2; nb >= 1 && !found; --nb)
    for (int gh = 8; gh >= 1 && !found; gh >>= 1)
      for (int gs = nb * gh; gs >= 1 && !found; gs >>= 1) {
        size_t need = fixed + al((size_t)nb * S_ * H_ * D_ * 2)
                    + al(2ULL * nb * gh * S_ * D_ * 2)
                    + al((size_t)nb * gh * D_ * S_ * 2)
                    + al(4ULL * nb * SD * 4)
                    + al((size_t)gs * eSS * 2)
                    + al((size_t)gs * 16 * S_ * 4);
        if (need <= ws_size) { NB = nb; GH = gh; GS = gs; found = true; }
      }

  char* p0 = (char*)d_ws;
  size_t off = 0;
  f16* xh    = (f16*)(p0 + off); off += al(eX * 2);
  f16* wqk   = (f16*)(p0 + off); off += al(2 * eW * 2);
  f16* wv    = (f16*)(p0 + off); off += al(eW * 2);
  f16* wo    = (f16*)(p0 + off); off += al(eW * 2);
  float* bqk = (float*)(p0 + off); off += al(2ULL * H_ * D_ * 4);
  f16* catb  = (f16*)(p0 + off); off += al((size_t)NB * S_ * H_ * D_ * 2);
  f16* qk    = (f16*)(p0 + off); off += al(2ULL * NB * GH * S_ * D_ * 2);
  f16* vT    = (f16*)(p0 + off); off += al((size_t)NB * GH * D_ * S_ * 2);
  float* opart = (float*)(p0 + off); off += al(4ULL * NB * SD * 4);
  f16* scores = (f16*)(p0 + off); off += al((size_t)GS * eSS * 2);
  float* mloc = (float*)(p0 + off);

  // ---- prep ----
  cvt_f16<<<dim3((unsigned)((eX + 255) / 256)), 256, 0, stream>>>(x, xh, (long)eX);
  dim3 tb(32, 8, 1);
  transpose_f32<<<dim3(16, 16, H_), tb, 0, stream>>>(Wq, wqk, D_, D_);
  transpose_f32<<<dim3(16, 16, H_), tb, 0, stream>>>(Wk, wqk + eW, D_, D_);
  transpose_f32<<<dim3(16, 16, H_), tb, 0, stream>>>(Wv, wv, D_, D_);
  transpose_f32<<<dim3(16, 128, 1), tb, 0, stream>>>(Wo, wo, H_ * D_, D_);
  hipMemcpyAsync(bqk, bq, (size_t)H_ * D_ * 4, hipMemcpyDeviceToDevice, stream);
  hipMemcpyAsync(bqk + H_ * D_, bk, (size_t)H_ * D_ * 4, hipMemcpyDeviceToDevice, stream);

  for (int b0 = 0; b0 < B_; b0 += NB) {
    for (int h0 = 0; h0 < H_; h0 += GH) {
      if (NB == 2 && GH == 8) {
        QkvArgs a{xh, wqk, wv, qk, vT, bqk, bv};
        qkv_proj<<<dim3(64, 1, 48), 256, 0, stream>>>(a);
      } else {
        {  // Q+K projections
          GemmArgs a{};
          a.A = xh + (long)b0 * SD;
          a.Bm = wqk + (long)h0 * DD;
          a.C = qk; a.bias = bqk + (long)h0 * D_;
          a.K = D_; a.lda = D_; a.ldb = D_; a.ldc = D_;
          a.zbase = 0; a.NG = GH; a.PBG = NB * GH;
          a.sAb = SD;
          a.sBp = (long)H_ * DD; a.sBg = DD;
          a.sCz = SD;
          a.sbp = (long)H_ * D_; a.sbg = D_;
          gemm_nt<f16, 1, false><<<dim3(4, 16, 2 * NB * GH), 256, 0, stream>>>(a);
        }
        {  // V^T
          GemmArgs a{};
          a.A = wv + (long)h0 * DD; a.Bm = xh + (long)b0 * SD;
          a.C = vT; a.bias = bv + (long)h0 * D_;
          a.K = D_; a.lda = D_; a.ldb = D_; a.ldc = S_;
          a.zbase = 0; a.NG = GH; a.PBG = NB * GH;
          a.sAg = DD;
          a.sBb = SD;
          a.sCz = DS;
          a.sbg = D_;
          gemm_nt<f16, 2, false><<<dim3(16, 4, NB * GH), 256, 0, stream>>>(a);
        }
      }
      for (int g0 = 0; g0 < NB * GH; g0 += GS) {
        {  // scores -> P_loc = exp(s - m_loc) f16, Mloc (no atomics)
          GemmArgs a{};
          a.A = qk + (long)g0 * SD;
          a.Bm = qk + ((long)NB * GH + g0) * SD;
          a.C = scores; a.Mloc = mloc;
          a.K = D_; a.lda = D_; a.ldb = D_; a.ldc = S_;
          a.zbase = g0; a.NG = GH; a.PBG = NB * GH;
          a.sAz = SD; a.sBz = SD; a.sCz = (long)eSS;
          a.sMlz = 16L * S_;
          gemm_nt<f16, 0, true><<<dim3(16, 16, GS), 256, 0, stream>>>(a);
        }
        {  // flash PV (rescale-only, 256-col e-blocks)
          PvArgs a{};
          a.S = scores; a.Ml = mloc; a.V = vT + (long)g0 * DS;
          a.C = catb + (long)h0 * D_;
          a.ldc = H_ * D_; a.zbase = g0; a.NG = GH;
          a.sVz = DS; a.sCb = (long)S_ * H_ * D_; a.sCg = D_;
          pv_flash<<<dim3(2, S_ / 64, GS), 256, 0, stream>>>(a);
        }
      }
    }
    {  // out-proj split-K (4 slabs of 1024)
      GemmArgs a{};
      a.A = catb; a.Bm = wo;
      a.C = opart;
      a.K = 1024; a.lda = H_ * D_; a.ldb = H_ * D_; a.ldc = D_;
      a.zbase = 0; a.NG = 4; a.PBG = NB * 4;
      a.sAb = (long)S_ * H_ * D_; a.sAg = 1024;
      a.sBg = 1024;
      a.sCb = SD; a.sCg = (long)NB * SD;
      gemm_nt<float, 0, false><<<dim3(4, 16, NB * 4), 256, 0, stream>>>(a);
    }
    reduce_out<<<dim3((unsigned)(((long)NB * SD + 255) / 256)), 256, 0, stream>>>(
        opart, bo, out + (long)b0 * SD, (long)NB * SD, 4);
  }
}